// Round 10
// baseline (219.717 us; speedup 1.0000x reference)
//
#include <hip/hip_runtime.h>
#include <stdint.h>

#define N_ROWS 8192
#define DIM    128
#define NCODES 16384
#define TAU    0.01f
#define MARGIN_EMIT 0.16f   // emit if bf16 score > running strip max - this
#define RESCORE_WIN 0.15f   // finalize: exact-rescore keys within this of key-max
#define CAP    256
#define QDEPTH 16           // per-row per-block LDS queue depth

typedef __attribute__((ext_vector_type(4))) float f32x4;
typedef __attribute__((ext_vector_type(8))) short s16x8;

// ---------------- workspace layout (bytes) ----------------
// [0, 2 MiB)            : xbf  swizzled bf16 (fragment order)
// [2 MiB, 6 MiB)        : cbbf swizzled bf16 (fragment order)
// [6 MiB, +32 KiB)      : cnt  int[8192]
// [8 MiB, 16 MiB)       : cand uint[8192*256] packed (score18<<14 | idx)

__device__ inline unsigned short f2bf(float f) {
    union { float f; unsigned int u; } v; v.f = f;
    unsigned int r = v.u + 0x7FFFu + ((v.u >> 16) & 1u);  // RNE
    return (unsigned short)(r >> 16);
}

// ---------------- kernel A: convert + swizzle + zero cnt ----------------
// Fragment order: flat = ((tile*4 + kk)*64 + lane)*8 + e
//   tile = row/16, r = lane&15, q = lane>>4, src = M[tile*16+r][kk*32+q*8+e]
#define XGROUPS  131072   // 8192*128/8
#define CBGROUPS 262144   // 16384*128/8
__global__ void convert_kernel(const float* __restrict__ x, const float* __restrict__ cb,
                               unsigned short* __restrict__ xbf, unsigned short* __restrict__ cbbf,
                               int* __restrict__ cnt) {
    int gid = blockIdx.x * blockDim.x + threadIdx.x;
    if (gid < XGROUPS + CBGROUPS) {
        const float* src; unsigned short* dst; int g;
        if (gid < XGROUPS) { g = gid; src = x; dst = xbf; }
        else               { g = gid - XGROUPS; src = cb; dst = cbbf; }
        const int t = g >> 8, within = g & 255;
        const int kk = within >> 6, ln = within & 63;
        const int r = ln & 15, q = ln >> 4;
        // explicit float4 vector loads (G13: don't rely on auto-vectorization)
        const float4* p4 = reinterpret_cast<const float4*>(
            src + ((size_t)(t * 16 + r) * DIM + kk * 32 + q * 8));
        const float4 a = p4[0], b = p4[1];
        s16x8 v;
        v[0] = (short)f2bf(a.x); v[1] = (short)f2bf(a.y);
        v[2] = (short)f2bf(a.z); v[3] = (short)f2bf(a.w);
        v[4] = (short)f2bf(b.x); v[5] = (short)f2bf(b.y);
        v[6] = (short)f2bf(b.z); v[7] = (short)f2bf(b.w);
        *reinterpret_cast<s16x8*>(dst + (size_t)g * 8) = v;
    } else {
        int i = gid - (XGROUPS + CBGROUPS);
        if (i < N_ROWS) cnt[i] = 0;
    }
}

// ---------------- kernel B: MFMA scan, online self-seeded threshold ----------------
// r8 post-mortem: setprio null (122 vs 120, within noise) -> dropped; r6
// structure is the gemm plateau. This round removes the SEPARATE seed kernel:
// each block maintains a running per-row threshold thrv = max(thrv,
// rowmax(tile) - MARGIN_EMIT), updated BEFORE emission each tile.
// Correctness: thrv <= stripmax - 0.16 <= globalmax - 0.16 at all times, so
// any score within RESCORE_WIN=0.15 of the global row max clears thrv ->
// emitted (same guarantee the seeded scheme used: seedmax <= globalmax).
// Finalize's rescore semantics unchanged. Emission volume ~30-50/row total
// (8 self-seeded blocks) -- well under CAP; QDEPTH absorbs per-block.
// Row-consistent threshold needs the tile row-max across the 4 q-lanes:
// 2x shfl_xor (16,32) per xt per tile -- pure VALU, no new vmem.
// Geometry unchanged from r6: grid 1024 = 128 rowgroups x 8 csplits
// (csplit == XCD -> 512 KiB cb strip L2-resident, FETCH ~10 MB), (256,4),
// 1-ahead prefetch into other buffer, LDS emission queue + epilogue flush.
__global__ __launch_bounds__(256, 4) void gemm_topk_kernel(
        const unsigned short* __restrict__ xbf, const unsigned short* __restrict__ cbbf,
        int* __restrict__ cnt, unsigned int* __restrict__ cand) {
    __shared__ unsigned int qcnt[64];
    __shared__ unsigned int qdat[64][QDEPTH];   // 4 KiB
    const int wave = threadIdx.x >> 6, lane = threadIdx.x & 63;
    const int r = lane & 15, q = lane >> 4;
    const int rowgrp = blockIdx.x >> 3, csplit = blockIdx.x & 7;
    const int row0 = rowgrp * 64;

    if (threadIdx.x < 64) qcnt[threadIdx.x] = 0;

    // x fragments register-resident: 4 x-tiles x 4 k-steps = 64 VGPRs
    s16x8 bf[4][4];
#pragma unroll
    for (int xt = 0; xt < 4; ++xt)
#pragma unroll
        for (int kk = 0; kk < 4; ++kk)
            bf[xt][kk] = *reinterpret_cast<const s16x8*>(
                xbf + (((size_t)(rowgrp * 4 + xt) * 4 + kk) * 64 + lane) * 8);

    // online self-seeded thresholds (rise as the strip scan proceeds)
    float thrv[4];
#pragma unroll
    for (int xt = 0; xt < 4; ++xt) thrv[xt] = -1e30f;

    __syncthreads();   // qcnt init visible to all waves

    const int t0 = csplit * 128 + wave * 32;   // wave's 32 cb tiles (512 cb rows)

    // 32-bit element-offset streaming; one VGPR, +2048 ushorts (4 KiB) per tile
    unsigned off = ((unsigned)t0 * 256u + (unsigned)lane) * 8u;

    s16x8 af[2][4];
#pragma unroll
    for (int kk = 0; kk < 4; ++kk)
        af[0][kk] = *reinterpret_cast<const s16x8*>(cbbf + off + (unsigned)kk * 512u);
    off += 2048u;

    int cbase = t0 * 16 + q * 4;   // code index accumulator, +16 per tile

#pragma unroll 2
    for (int t = 0; t < 32; ++t) {
        // unconditional 1-ahead prefetch into the OTHER buffer: at t=31 this
        // reads 4 KiB past cbbf (cnt region -> valid memory, never consumed)
#pragma unroll
        for (int kk = 0; kk < 4; ++kk)
            af[(t + 1) & 1][kk] = *reinterpret_cast<const s16x8*>(
                cbbf + off + (unsigned)kk * 512u);
        off += 2048u;

        const s16x8* cur = af[t & 1];

        f32x4 acc[4];
#pragma unroll
        for (int xt = 0; xt < 4; ++xt) acc[xt] = (f32x4){0.f, 0.f, 0.f, 0.f};
#pragma unroll
        for (int kk = 0; kk < 4; ++kk)
#pragma unroll
            for (int xt = 0; xt < 4; ++xt)
                acc[xt] = __builtin_amdgcn_mfma_f32_16x16x32_bf16(
                    cur[kk], bf[xt][kk], acc[xt], 0, 0, 0);

        // update running threshold, then emit (update-then-emit keeps the
        // guarantee and minimizes emissions)
#pragma unroll
        for (int xt = 0; xt < 4; ++xt) {
            const float mx = fmaxf(fmaxf(acc[xt][0], acc[xt][1]),
                                   fmaxf(acc[xt][2], acc[xt][3]));
            float rowmx = fmaxf(mx, __shfl_xor(mx, 16));
            rowmx = fmaxf(rowmx, __shfl_xor(rowmx, 32));
            thrv[xt] = fmaxf(thrv[xt], rowmx - MARGIN_EMIT);
            if (mx > thrv[xt]) {
                const int lrow = xt * 16 + r;
#pragma unroll
                for (int j = 0; j < 4; ++j)
                    if (acc[xt][j] > thrv[xt]) {
                        // score > 0 here, so float bits are monotone
                        unsigned int key = ((__float_as_uint(acc[xt][j]) >> 13) << 14)
                                         | (unsigned int)(cbase + j);
                        unsigned int p = atomicAdd(&qcnt[lrow], 1u);  // ds_add_rtn
                        if (p < QDEPTH) {
                            qdat[lrow][p] = key;
                        } else {
                            // overflow fallback: direct global emit (rare)
                            int pos = atomicAdd(&cnt[row0 + lrow], 1);
                            if (pos < CAP) cand[(size_t)(row0 + lrow) * CAP + pos] = key;
                        }
                    }
            }
        }
        cbase += 16;
    }

    // epilogue: one global atomic per non-empty row, bulk store
    __syncthreads();
    if (threadIdx.x < 64) {
        const int lrow = threadIdx.x;
        unsigned int k = qcnt[lrow];
        if (k > QDEPTH) k = QDEPTH;
        if (k) {
            const int grow = row0 + lrow;
            int pos = atomicAdd(&cnt[grow], (int)k);
            for (unsigned int i = 0; i < k; ++i) {
                int p2 = pos + (int)i;
                if (p2 < CAP) cand[(size_t)grow * CAP + p2] = qdat[lrow][i];
            }
        }
    }
}

// ---------------- kernel C: key scan + exact fp32 rescore of near-max + softmax ----------------
__device__ inline void topk3_insert(float s, int i, float& s1, int& i1,
                                    float& s2, int& i2, float& s3, int& i3) {
    if (s > s1 || (s == s1 && i < i1)) {
        s3 = s2; i3 = i2; s2 = s1; i2 = i1; s1 = s; i1 = i;
    } else if (s > s2 || (s == s2 && i < i2)) {
        s3 = s2; i3 = i2; s2 = s; i2 = i;
    } else if (s > s3 || (s == s3 && i < i3)) {
        s3 = s; i3 = i;
    }
}

__device__ inline float dec_key(unsigned int k) {
    return __uint_as_float((k >> 14) << 13);
}

__global__ __launch_bounds__(256) void finalize_kernel(
        const float* __restrict__ x, const float* __restrict__ cb,
        const int* __restrict__ cnt, const unsigned int* __restrict__ cand,
        float* __restrict__ out) {
    const int lane = threadIdx.x & 63;
    const int row  = blockIdx.x * 4 + (threadIdx.x >> 6);

    int c = cnt[row];
    if (c > CAP) c = CAP;
    if (c < 0) c = 0;

    const float2 xv = ((const float2*)x)[(size_t)row * 64 + lane];

    // pass 1: max key (coalesced)
    unsigned int kmax = 0;
    for (int i = lane; i < c; i += 64)
        kmax = max(kmax, cand[(size_t)row * CAP + i]);
#pragma unroll
    for (int d = 1; d < 64; d <<= 1)
        kmax = max(kmax, (unsigned int)__shfl_xor((int)kmax, d));
    const float rthr = dec_key(kmax) - RESCORE_WIN;

    // pass 2: exact-rescore candidates near the max (expected ~2)
    const int BIGI = 0x3FFFFFFF;
    float fs1 = -1e30f, fs2 = -1e30f, fs3 = -1e30f;
    int   fi1 = BIGI,   fi2 = BIGI,   fi3 = BIGI;
    for (int basei = 0; basei < c; basei += 64) {
        const int i = basei + lane;
        unsigned int key = (i < c) ? cand[(size_t)row * CAP + i] : 0u;
        const bool flag = (i < c) && (dec_key(key) > rthr);
        unsigned long long mask = __ballot(flag);
        while (mask) {
            const int b = __ffsll((long long)mask) - 1;
            mask &= mask - 1;
            const int idx = __shfl((int)(key & 16383u), b);
            const float2 cv = ((const float2*)cb)[(size_t)idx * 64 + lane];
            float p = xv.x * cv.x + xv.y * cv.y;
#pragma unroll
            for (int d = 1; d < 64; d <<= 1) p += __shfl_xor(p, d);
            topk3_insert(p, idx, fs1, fi1, fs2, fi2, fs3, fi3);
        }
    }

    // exact softmax over {top-3} U {C-3 zeros}
    const float m  = fmaxf(fs1, 0.f);
    const float e1 = (fi1 != BIGI) ? __expf((fs1 - m) / TAU) : 0.f;
    const float e2 = (fi2 != BIGI) ? __expf((fs2 - m) / TAU) : 0.f;
    const float e3 = (fi3 != BIGI) ? __expf((fs3 - m) / TAU) : 0.f;
    const float denom = e1 + e2 + e3 + (float)(NCODES - 3) * __expf(-m / TAU);
    const float w1 = e1 / denom, w2 = e2 / denom, w3 = e3 / denom;

    const float2* cb2 = (const float2*)cb;
    float ox = 0.f, oy = 0.f;
    if (fi1 != BIGI) { float2 v = cb2[(size_t)fi1 * 64 + lane]; ox += w1 * v.x; oy += w1 * v.y; }
    if (fi2 != BIGI) { float2 v = cb2[(size_t)fi2 * 64 + lane]; ox += w2 * v.x; oy += w2 * v.y; }
    if (fi3 != BIGI) { float2 v = cb2[(size_t)fi3 * 64 + lane]; ox += w3 * v.x; oy += w3 * v.y; }
    ((float2*)out)[(size_t)row * 64 + lane] = make_float2(ox, oy);
}

// ---------------- launch ----------------
extern "C" void kernel_launch(void* const* d_in, const int* in_sizes, int n_in,
                              void* d_out, int out_size, void* d_ws, size_t ws_size,
                              hipStream_t stream) {
    const float* x  = (const float*)d_in[0];
    const float* cb = (const float*)d_in[1];
    char* ws = (char*)d_ws;

    unsigned short* xbf  = (unsigned short*)ws;                         // 2 MiB
    unsigned short* cbbf = (unsigned short*)(ws + (2u << 20));          // 4 MiB
    int* cnt  = (int*)(ws + (6u << 20));                                // 32 KiB
    unsigned int* cand = (unsigned int*)(ws + (8u << 20));              // 8 MiB
    float* out = (float*)d_out;

    hipLaunchKernelGGL(convert_kernel,   dim3(1600), dim3(256), 0, stream, x, cb, xbf, cbbf, cnt);
    hipLaunchKernelGGL(gemm_topk_kernel, dim3(1024), dim3(256), 0, stream, xbf, cbbf, cnt, cand);
    hipLaunchKernelGGL(finalize_kernel,  dim3(2048), dim3(256), 0, stream, x, cb, cnt, cand, out);
}

// Round 11
// 121.040 us; speedup vs baseline: 1.8152x; 1.8152x over previous
//
#include <hip/hip_runtime.h>
#include <stdint.h>

#define N_ROWS 8192
#define DIM    128
#define NCODES 16384
#define TAU    0.01f
#define MARGIN_EMIT 0.16f   // emit if bf16 score > approx_rowmax - this
#define RESCORE_WIN 0.15f   // finalize: exact-rescore keys within this of key-max
#define CAP    256
#define QDEPTH 16           // per-row per-block LDS queue depth (expected ~0.75 used)

typedef __attribute__((ext_vector_type(4))) float f32x4;
typedef __attribute__((ext_vector_type(8))) short s16x8;

// ---------------- workspace layout (bytes) ----------------
// [0, 2 MiB)            : xbf  swizzled bf16 (fragment order)
// [2 MiB, 6 MiB)        : cbbf swizzled bf16 (fragment order)
// [6 MiB, +32 KiB)      : cnt  int[8192]
// [6 MiB+128K, +32 KiB) : thr  int[8192] (int-punned float, seeded approx row max)
// [8 MiB, 16 MiB)       : cand uint[8192*256] packed (score18<<14 | idx)

__device__ inline unsigned short f2bf(float f) {
    union { float f; unsigned int u; } v; v.f = f;
    unsigned int r = v.u + 0x7FFFu + ((v.u >> 16) & 1u);  // RNE
    return (unsigned short)(r >> 16);
}

// ---------------- kernel A: convert + swizzle + zero cnt/thr ----------------
// Fragment order: flat = ((tile*4 + kk)*64 + lane)*8 + e
//   tile = row/16, r = lane&15, q = lane>>4, src = M[tile*16+r][kk*32+q*8+e]
#define XGROUPS  131072   // 8192*128/8
#define CBGROUPS 262144   // 16384*128/8
__global__ void convert_kernel(const float* __restrict__ x, const float* __restrict__ cb,
                               unsigned short* __restrict__ xbf, unsigned short* __restrict__ cbbf,
                               int* __restrict__ cnt, int* __restrict__ thr) {
    int gid = blockIdx.x * blockDim.x + threadIdx.x;
    if (gid < XGROUPS + CBGROUPS) {
        const float* src; unsigned short* dst; int g;
        if (gid < XGROUPS) { g = gid; src = x; dst = xbf; }
        else               { g = gid - XGROUPS; src = cb; dst = cbbf; }
        const int t = g >> 8, within = g & 255;
        const int kk = within >> 6, ln = within & 63;
        const int r = ln & 15, q = ln >> 4;
        // explicit float4 vector loads (G13: don't rely on auto-vectorization)
        const float4* p4 = reinterpret_cast<const float4*>(
            src + ((size_t)(t * 16 + r) * DIM + kk * 32 + q * 8));
        const float4 a = p4[0], b = p4[1];
        s16x8 v;
        v[0] = (short)f2bf(a.x); v[1] = (short)f2bf(a.y);
        v[2] = (short)f2bf(a.z); v[3] = (short)f2bf(a.w);
        v[4] = (short)f2bf(b.x); v[5] = (short)f2bf(b.y);
        v[6] = (short)f2bf(b.z); v[7] = (short)f2bf(b.w);
        *reinterpret_cast<s16x8*>(dst + (size_t)g * 8) = v;
    } else {
        int i = gid - (XGROUPS + CBGROUPS);
        if (i < N_ROWS) cnt[i] = 0;
        else if (i < 2 * N_ROWS) thr[i - N_ROWS] = 0;   // 0.0f bits; scores' max > 0 always
    }
}

// ---------------- kernel S: seed approx per-row max over cb rows [0, 2048) ----------------
// r10 post-mortem: the separate seed kernel is ESSENTIAL. Its cross-block
// shared max over 2048 cb rows (~3.3 sigma) lets every scan block emit ~6/row
// total; a block-local running threshold (r10) gave ~200/row (QDEPTH overflow,
// 568k LDS conflicts, gemm 37->145us). Seed's ~6us is well spent.
// r3 gemm template: grid 1024 = 128 rowgroups(64 rows) x 8 csplits, (256,4);
// wave scans 4 tiles with 32-bit element-offset streaming + 1-ahead prefetch
// (last prefetch reads tile t0+4 <= 128, inside cbbf, never consumed).
__global__ __launch_bounds__(256, 4) void seed_kernel(
        const unsigned short* __restrict__ xbf, const unsigned short* __restrict__ cbbf,
        int* __restrict__ thr) {
    __shared__ int rm[64];
    const int wave = threadIdx.x >> 6, lane = threadIdx.x & 63;
    const int r = lane & 15;
    const int rowgrp = blockIdx.x >> 3, csplit = blockIdx.x & 7;
    if (threadIdx.x < 64) rm[threadIdx.x] = 0;
    __syncthreads();

    s16x8 bf[4][4];
#pragma unroll
    for (int xt = 0; xt < 4; ++xt)
#pragma unroll
        for (int kk = 0; kk < 4; ++kk)
            bf[xt][kk] = *reinterpret_cast<const s16x8*>(
                xbf + (((size_t)(rowgrp * 4 + xt) * 4 + kk) * 64 + lane) * 8);

    const int t0 = (csplit * 4 + wave) * 4;   // 32 waves/rowgroup x 4 tiles = tiles 0..127
    unsigned off = ((unsigned)t0 * 256u + (unsigned)lane) * 8u;

    s16x8 af[2][4];
#pragma unroll
    for (int kk = 0; kk < 4; ++kk)
        af[0][kk] = *reinterpret_cast<const s16x8*>(cbbf + off + (unsigned)kk * 512u);
    off += 2048u;

    float mxv[4] = {0.f, 0.f, 0.f, 0.f};
#pragma unroll 2
    for (int t = 0; t < 4; ++t) {
#pragma unroll
        for (int kk = 0; kk < 4; ++kk)
            af[(t + 1) & 1][kk] = *reinterpret_cast<const s16x8*>(
                cbbf + off + (unsigned)kk * 512u);
        off += 2048u;

        const s16x8* cur = af[t & 1];
        f32x4 acc[4];
#pragma unroll
        for (int xt = 0; xt < 4; ++xt) acc[xt] = (f32x4){0.f, 0.f, 0.f, 0.f};
#pragma unroll
        for (int kk = 0; kk < 4; ++kk)
#pragma unroll
            for (int xt = 0; xt < 4; ++xt)
                acc[xt] = __builtin_amdgcn_mfma_f32_16x16x32_bf16(
                    cur[kk], bf[xt][kk], acc[xt], 0, 0, 0);
#pragma unroll
        for (int xt = 0; xt < 4; ++xt)
            mxv[xt] = fmaxf(mxv[xt],
                fmaxf(fmaxf(acc[xt][0], acc[xt][1]), fmaxf(acc[xt][2], acc[xt][3])));
    }
#pragma unroll
    for (int xt = 0; xt < 4; ++xt)
        atomicMax(&rm[xt * 16 + r], __float_as_int(mxv[xt]));
    __syncthreads();
    if (threadIdx.x < 64)
        atomicMax(&thr[rowgrp * 64 + threadIdx.x], rm[threadIdx.x]);
}

// ---------------- kernel B: r6 structure (verified 120us total) ----------------
// Verified plateau config: grid 1024 = 128 rowgroups x 8 csplits (csplit ==
// XCD under round-robin -> 512 KiB cb strip L2-resident, FETCH ~10 MB),
// (256,4), bf[4][4] in regs, double-buffered af with 1-ahead prefetch into
// the OTHER buffer BEFORE the MFMA cluster, 32-bit element-offset streaming,
// fixed seeded thresholds, LDS emission queue + epilogue flush (keeps global
// atomics out of the main loop's vmcnt FIFO -- r6's +11us win).
// Ruled out by A/B on this structure: setprio (r8 null), dist-2 prefetch-
// after-MFMA (r7: WAR->spills), self-seeded threshold (r10: 30x emissions),
// 8-waves/SIMD via LDS-bf (r5: broke csplit==XCD + reg budget).
__global__ __launch_bounds__(256, 4) void gemm_topk_kernel(
        const unsigned short* __restrict__ xbf, const unsigned short* __restrict__ cbbf,
        const int* __restrict__ thr, int* __restrict__ cnt, unsigned int* __restrict__ cand) {
    __shared__ unsigned int qcnt[64];
    __shared__ unsigned int qdat[64][QDEPTH];   // 4 KiB
    const int wave = threadIdx.x >> 6, lane = threadIdx.x & 63;
    const int r = lane & 15, q = lane >> 4;
    const int rowgrp = blockIdx.x >> 3, csplit = blockIdx.x & 7;
    const int row0 = rowgrp * 64;

    if (threadIdx.x < 64) qcnt[threadIdx.x] = 0;

    // x fragments register-resident: 4 x-tiles x 4 k-steps = 64 VGPRs
    s16x8 bf[4][4];
#pragma unroll
    for (int xt = 0; xt < 4; ++xt)
#pragma unroll
        for (int kk = 0; kk < 4; ++kk)
            bf[xt][kk] = *reinterpret_cast<const s16x8*>(
                xbf + (((size_t)(rowgrp * 4 + xt) * 4 + kk) * 64 + lane) * 8);

    // fixed emission thresholds (seeded approx max - margin)
    float thrv[4];
#pragma unroll
    for (int xt = 0; xt < 4; ++xt)
        thrv[xt] = __int_as_float(thr[row0 + xt * 16 + r]) - MARGIN_EMIT;

    __syncthreads();   // qcnt init visible to all waves

    const int t0 = csplit * 128 + wave * 32;   // wave's 32 cb tiles (512 cb rows)

    // 32-bit element-offset streaming; one VGPR, +2048 ushorts (4 KiB) per tile
    unsigned off = ((unsigned)t0 * 256u + (unsigned)lane) * 8u;

    s16x8 af[2][4];
#pragma unroll
    for (int kk = 0; kk < 4; ++kk)
        af[0][kk] = *reinterpret_cast<const s16x8*>(cbbf + off + (unsigned)kk * 512u);
    off += 2048u;

    int cbase = t0 * 16 + q * 4;   // code index accumulator, +16 per tile

#pragma unroll 2
    for (int t = 0; t < 32; ++t) {
        // unconditional 1-ahead prefetch into the OTHER buffer: at t=31 this
        // reads 4 KiB past cbbf (cnt/thr region -> valid memory, never consumed)
#pragma unroll
        for (int kk = 0; kk < 4; ++kk)
            af[(t + 1) & 1][kk] = *reinterpret_cast<const s16x8*>(
                cbbf + off + (unsigned)kk * 512u);
        off += 2048u;

        const s16x8* cur = af[t & 1];

        f32x4 acc[4];
#pragma unroll
        for (int xt = 0; xt < 4; ++xt) acc[xt] = (f32x4){0.f, 0.f, 0.f, 0.f};
#pragma unroll
        for (int kk = 0; kk < 4; ++kk)
#pragma unroll
            for (int xt = 0; xt < 4; ++xt)
                acc[xt] = __builtin_amdgcn_mfma_f32_16x16x32_bf16(
                    cur[kk], bf[xt][kk], acc[xt], 0, 0, 0);

        // fixed-threshold emission into LDS queue (rare: ~6 per row over scan)
#pragma unroll
        for (int xt = 0; xt < 4; ++xt) {
            const float mx = fmaxf(fmaxf(acc[xt][0], acc[xt][1]),
                                   fmaxf(acc[xt][2], acc[xt][3]));
            if (mx > thrv[xt]) {
                const int lrow = xt * 16 + r;
#pragma unroll
                for (int j = 0; j < 4; ++j)
                    if (acc[xt][j] > thrv[xt]) {
                        // score > 0 here, so float bits are monotone
                        unsigned int key = ((__float_as_uint(acc[xt][j]) >> 13) << 14)
                                         | (unsigned int)(cbase + j);
                        unsigned int p = atomicAdd(&qcnt[lrow], 1u);  // ds_add_rtn
                        if (p < QDEPTH) {
                            qdat[lrow][p] = key;
                        } else {
                            // overflow fallback: direct global emit (rare)
                            int pos = atomicAdd(&cnt[row0 + lrow], 1);
                            if (pos < CAP) cand[(size_t)(row0 + lrow) * CAP + pos] = key;
                        }
                    }
            }
        }
        cbase += 16;
    }

    // epilogue: one global atomic per non-empty row, bulk store
    __syncthreads();
    if (threadIdx.x < 64) {
        const int lrow = threadIdx.x;
        unsigned int k = qcnt[lrow];
        if (k > QDEPTH) k = QDEPTH;
        if (k) {
            const int grow = row0 + lrow;
            int pos = atomicAdd(&cnt[grow], (int)k);
            for (unsigned int i = 0; i < k; ++i) {
                int p2 = pos + (int)i;
                if (p2 < CAP) cand[(size_t)grow * CAP + p2] = qdat[lrow][i];
            }
        }
    }
}

// ---------------- kernel C: key scan + exact fp32 rescore of near-max + softmax ----------------
__device__ inline void topk3_insert(float s, int i, float& s1, int& i1,
                                    float& s2, int& i2, float& s3, int& i3) {
    if (s > s1 || (s == s1 && i < i1)) {
        s3 = s2; i3 = i2; s2 = s1; i2 = i1; s1 = s; i1 = i;
    } else if (s > s2 || (s == s2 && i < i2)) {
        s3 = s2; i3 = i2; s2 = s; i2 = i;
    } else if (s > s3 || (s == s3 && i < i3)) {
        s3 = s; i3 = i;
    }
}

__device__ inline float dec_key(unsigned int k) {
    return __uint_as_float((k >> 14) << 13);
}

__global__ __launch_bounds__(256) void finalize_kernel(
        const float* __restrict__ x, const float* __restrict__ cb,
        const int* __restrict__ cnt, const unsigned int* __restrict__ cand,
        float* __restrict__ out) {
    const int lane = threadIdx.x & 63;
    const int row  = blockIdx.x * 4 + (threadIdx.x >> 6);

    int c = cnt[row];
    if (c > CAP) c = CAP;
    if (c < 0) c = 0;

    const float2 xv = ((const float2*)x)[(size_t)row * 64 + lane];

    // pass 1: max key (coalesced)
    unsigned int kmax = 0;
    for (int i = lane; i < c; i += 64)
        kmax = max(kmax, cand[(size_t)row * CAP + i]);
#pragma unroll
    for (int d = 1; d < 64; d <<= 1)
        kmax = max(kmax, (unsigned int)__shfl_xor((int)kmax, d));
    const float rthr = dec_key(kmax) - RESCORE_WIN;

    // pass 2: exact-rescore candidates near the max (expected ~2)
    const int BIGI = 0x3FFFFFFF;
    float fs1 = -1e30f, fs2 = -1e30f, fs3 = -1e30f;
    int   fi1 = BIGI,   fi2 = BIGI,   fi3 = BIGI;
    for (int basei = 0; basei < c; basei += 64) {
        const int i = basei + lane;
        unsigned int key = (i < c) ? cand[(size_t)row * CAP + i] : 0u;
        const bool flag = (i < c) && (dec_key(key) > rthr);
        unsigned long long mask = __ballot(flag);
        while (mask) {
            const int b = __ffsll((long long)mask) - 1;
            mask &= mask - 1;
            const int idx = __shfl((int)(key & 16383u), b);
            const float2 cv = ((const float2*)cb)[(size_t)idx * 64 + lane];
            float p = xv.x * cv.x + xv.y * cv.y;
#pragma unroll
            for (int d = 1; d < 64; d <<= 1) p += __shfl_xor(p, d);
            topk3_insert(p, idx, fs1, fi1, fs2, fi2, fs3, fi3);
        }
    }

    // exact softmax over {top-3} U {C-3 zeros}
    const float m  = fmaxf(fs1, 0.f);
    const float e1 = (fi1 != BIGI) ? __expf((fs1 - m) / TAU) : 0.f;
    const float e2 = (fi2 != BIGI) ? __expf((fs2 - m) / TAU) : 0.f;
    const float e3 = (fi3 != BIGI) ? __expf((fs3 - m) / TAU) : 0.f;
    const float denom = e1 + e2 + e3 + (float)(NCODES - 3) * __expf(-m / TAU);
    const float w1 = e1 / denom, w2 = e2 / denom, w3 = e3 / denom;

    const float2* cb2 = (const float2*)cb;
    float ox = 0.f, oy = 0.f;
    if (fi1 != BIGI) { float2 v = cb2[(size_t)fi1 * 64 + lane]; ox += w1 * v.x; oy += w1 * v.y; }
    if (fi2 != BIGI) { float2 v = cb2[(size_t)fi2 * 64 + lane]; ox += w2 * v.x; oy += w2 * v.y; }
    if (fi3 != BIGI) { float2 v = cb2[(size_t)fi3 * 64 + lane]; ox += w3 * v.x; oy += w3 * v.y; }
    ((float2*)out)[(size_t)row * 64 + lane] = make_float2(ox, oy);
}

// ---------------- launch ----------------
extern "C" void kernel_launch(void* const* d_in, const int* in_sizes, int n_in,
                              void* d_out, int out_size, void* d_ws, size_t ws_size,
                              hipStream_t stream) {
    const float* x  = (const float*)d_in[0];
    const float* cb = (const float*)d_in[1];
    char* ws = (char*)d_ws;

    unsigned short* xbf  = (unsigned short*)ws;                         // 2 MiB
    unsigned short* cbbf = (unsigned short*)(ws + (2u << 20));          // 4 MiB
    int* cnt  = (int*)(ws + (6u << 20));                                // 32 KiB
    int* thr  = (int*)(ws + (6u << 20) + (128u << 10));                 // 32 KiB
    unsigned int* cand = (unsigned int*)(ws + (8u << 20));              // 8 MiB
    float* out = (float*)d_out;

    hipLaunchKernelGGL(convert_kernel,   dim3(1600), dim3(256), 0, stream, x, cb, xbf, cbbf, cnt, thr);
    hipLaunchKernelGGL(seed_kernel,      dim3(1024), dim3(256), 0, stream, xbf, cbbf, thr);
    hipLaunchKernelGGL(gemm_topk_kernel, dim3(1024), dim3(256), 0, stream, xbf, cbbf, thr, cnt, cand);
    hipLaunchKernelGGL(finalize_kernel,  dim3(2048), dim3(256), 0, stream, x, cb, cnt, cand, out);
}

// Round 14
// 119.685 us; speedup vs baseline: 1.8358x; 1.0113x over previous
//
#include <hip/hip_runtime.h>
#include <stdint.h>

#define N_ROWS 8192
#define DIM    128
#define NCODES 16384
#define TAU    0.01f
#define MARGIN_EMIT 0.16f   // emit if bf16 score > approx_rowmax - this
#define RESCORE_WIN 0.15f   // finalize: exact-rescore keys within this of key-max
#define CAP    256
#define QDEPTH 16           // per-row per-block LDS queue depth (expected ~0.75 used)

typedef __attribute__((ext_vector_type(4))) float f32x4;
typedef __attribute__((ext_vector_type(8))) short s16x8;

// ---------------- workspace layout (bytes) ----------------
// [0, 2 MiB)            : xbf  swizzled bf16 (fragment order)
// [2 MiB, 6 MiB)        : cbbf swizzled bf16 (fragment order)
// [6 MiB, +32 KiB)      : cnt  int[8192]
// [6 MiB+128K, +32 KiB) : thr  int[8192] (int-punned float, seeded approx row max)
// [8 MiB, 16 MiB)       : cand uint[8192*256] packed (score18<<14 | idx)
//
// r13 post-mortem: cooperative-launch fusion NEVER RAN under the harness's
// graph capture (absmax 0.4375 == max|ref| vs zeroed out-buffer, bit-identical
// across two fence variants -> launch silently dropped, not a memory race).
// hipLaunchCooperativeKernel is incompatible with graph capture here; the
// 4-kernel stream-ordered pipeline is the only phase-sync mechanism.
// This file is the verified r11/r6 configuration (120.0/121.0 us measured).

__device__ inline unsigned short f2bf(float f) {
    union { float f; unsigned int u; } v; v.f = f;
    unsigned int r = v.u + 0x7FFFu + ((v.u >> 16) & 1u);  // RNE
    return (unsigned short)(r >> 16);
}

// ---------------- kernel A: convert + swizzle + zero cnt/thr ----------------
// Fragment order: flat = ((tile*4 + kk)*64 + lane)*8 + e
//   tile = row/16, r = lane&15, q = lane>>4, src = M[tile*16+r][kk*32+q*8+e]
#define XGROUPS  131072   // 8192*128/8
#define CBGROUPS 262144   // 16384*128/8
__global__ void convert_kernel(const float* __restrict__ x, const float* __restrict__ cb,
                               unsigned short* __restrict__ xbf, unsigned short* __restrict__ cbbf,
                               int* __restrict__ cnt, int* __restrict__ thr) {
    int gid = blockIdx.x * blockDim.x + threadIdx.x;
    if (gid < XGROUPS + CBGROUPS) {
        const float* src; unsigned short* dst; int g;
        if (gid < XGROUPS) { g = gid; src = x; dst = xbf; }
        else               { g = gid - XGROUPS; src = cb; dst = cbbf; }
        const int t = g >> 8, within = g & 255;
        const int kk = within >> 6, ln = within & 63;
        const int r = ln & 15, q = ln >> 4;
        // explicit float4 vector loads (G13: don't rely on auto-vectorization)
        const float4* p4 = reinterpret_cast<const float4*>(
            src + ((size_t)(t * 16 + r) * DIM + kk * 32 + q * 8));
        const float4 a = p4[0], b = p4[1];
        s16x8 v;
        v[0] = (short)f2bf(a.x); v[1] = (short)f2bf(a.y);
        v[2] = (short)f2bf(a.z); v[3] = (short)f2bf(a.w);
        v[4] = (short)f2bf(b.x); v[5] = (short)f2bf(b.y);
        v[6] = (short)f2bf(b.z); v[7] = (short)f2bf(b.w);
        *reinterpret_cast<s16x8*>(dst + (size_t)g * 8) = v;
    } else {
        int i = gid - (XGROUPS + CBGROUPS);
        if (i < N_ROWS) cnt[i] = 0;
        else if (i < 2 * N_ROWS) thr[i - N_ROWS] = 0;   // 0.0f bits; scores' max > 0 always
    }
}

// ---------------- kernel S: seed approx per-row max over cb rows [0, 2048) ----------------
// Cross-block shared seed max (~3.3 sigma over 2048 rows) keeps scan
// emissions at ~6/row; block-local alternatives gave ~200/row (r10).
// grid 1024 = 128 rowgroups(64 rows) x 8 csplits, (256,4); wave scans 4 tiles
// with 32-bit element-offset streaming + 1-ahead prefetch (last prefetch
// reads tile t0+4 <= 128, inside cbbf, never consumed).
__global__ __launch_bounds__(256, 4) void seed_kernel(
        const unsigned short* __restrict__ xbf, const unsigned short* __restrict__ cbbf,
        int* __restrict__ thr) {
    __shared__ int rm[64];
    const int wave = threadIdx.x >> 6, lane = threadIdx.x & 63;
    const int r = lane & 15;
    const int rowgrp = blockIdx.x >> 3, csplit = blockIdx.x & 7;
    if (threadIdx.x < 64) rm[threadIdx.x] = 0;
    __syncthreads();

    s16x8 bf[4][4];
#pragma unroll
    for (int xt = 0; xt < 4; ++xt)
#pragma unroll
        for (int kk = 0; kk < 4; ++kk)
            bf[xt][kk] = *reinterpret_cast<const s16x8*>(
                xbf + (((size_t)(rowgrp * 4 + xt) * 4 + kk) * 64 + lane) * 8);

    const int t0 = (csplit * 4 + wave) * 4;   // 32 waves/rowgroup x 4 tiles = tiles 0..127
    unsigned off = ((unsigned)t0 * 256u + (unsigned)lane) * 8u;

    s16x8 af[2][4];
#pragma unroll
    for (int kk = 0; kk < 4; ++kk)
        af[0][kk] = *reinterpret_cast<const s16x8*>(cbbf + off + (unsigned)kk * 512u);
    off += 2048u;

    float mxv[4] = {0.f, 0.f, 0.f, 0.f};
#pragma unroll 2
    for (int t = 0; t < 4; ++t) {
#pragma unroll
        for (int kk = 0; kk < 4; ++kk)
            af[(t + 1) & 1][kk] = *reinterpret_cast<const s16x8*>(
                cbbf + off + (unsigned)kk * 512u);
        off += 2048u;

        const s16x8* cur = af[t & 1];
        f32x4 acc[4];
#pragma unroll
        for (int xt = 0; xt < 4; ++xt) acc[xt] = (f32x4){0.f, 0.f, 0.f, 0.f};
#pragma unroll
        for (int kk = 0; kk < 4; ++kk)
#pragma unroll
            for (int xt = 0; xt < 4; ++xt)
                acc[xt] = __builtin_amdgcn_mfma_f32_16x16x32_bf16(
                    cur[kk], bf[xt][kk], acc[xt], 0, 0, 0);
#pragma unroll
        for (int xt = 0; xt < 4; ++xt)
            mxv[xt] = fmaxf(mxv[xt],
                fmaxf(fmaxf(acc[xt][0], acc[xt][1]), fmaxf(acc[xt][2], acc[xt][3])));
    }
#pragma unroll
    for (int xt = 0; xt < 4; ++xt)
        atomicMax(&rm[xt * 16 + r], __float_as_int(mxv[xt]));
    __syncthreads();
    if (threadIdx.x < 64)
        atomicMax(&thr[rowgrp * 64 + threadIdx.x], rm[threadIdx.x]);
}

// ---------------- kernel B: r6 structure (verified 120-121us total) ----------------
// Verified plateau config: grid 1024 = 128 rowgroups x 8 csplits (csplit ==
// XCD under round-robin -> 512 KiB cb strip L2-resident, FETCH ~10 MB),
// (256,4), bf[4][4] in regs, double-buffered af with 1-ahead prefetch into
// the OTHER buffer BEFORE the MFMA cluster, 32-bit element-offset streaming,
// fixed seeded thresholds, LDS emission queue + epilogue flush (keeps global
// atomics out of the main loop's vmcnt FIFO).
// Ruled out by A/B on this structure: setprio (r8 null), dist-2 prefetch-
// after-MFMA (r7: WAR->spills), self-seeded threshold (r10: 30x emissions),
// 8-waves/SIMD via LDS-bf (r5: broke csplit==XCD + reg budget), cooperative
// fusion (r12/r13: launch dropped under graph capture).
__global__ __launch_bounds__(256, 4) void gemm_topk_kernel(
        const unsigned short* __restrict__ xbf, const unsigned short* __restrict__ cbbf,
        const int* __restrict__ thr, int* __restrict__ cnt, unsigned int* __restrict__ cand) {
    __shared__ unsigned int qcnt[64];
    __shared__ unsigned int qdat[64][QDEPTH];   // 4 KiB
    const int wave = threadIdx.x >> 6, lane = threadIdx.x & 63;
    const int r = lane & 15, q = lane >> 4;
    const int rowgrp = blockIdx.x >> 3, csplit = blockIdx.x & 7;
    const int row0 = rowgrp * 64;

    if (threadIdx.x < 64) qcnt[threadIdx.x] = 0;

    // x fragments register-resident: 4 x-tiles x 4 k-steps = 64 VGPRs
    s16x8 bf[4][4];
#pragma unroll
    for (int xt = 0; xt < 4; ++xt)
#pragma unroll
        for (int kk = 0; kk < 4; ++kk)
            bf[xt][kk] = *reinterpret_cast<const s16x8*>(
                xbf + (((size_t)(rowgrp * 4 + xt) * 4 + kk) * 64 + lane) * 8);

    // fixed emission thresholds (seeded approx max - margin)
    float thrv[4];
#pragma unroll
    for (int xt = 0; xt < 4; ++xt)
        thrv[xt] = __int_as_float(thr[row0 + xt * 16 + r]) - MARGIN_EMIT;

    __syncthreads();   // qcnt init visible to all waves

    const int t0 = csplit * 128 + wave * 32;   // wave's 32 cb tiles (512 cb rows)

    // 32-bit element-offset streaming; one VGPR, +2048 ushorts (4 KiB) per tile
    unsigned off = ((unsigned)t0 * 256u + (unsigned)lane) * 8u;

    s16x8 af[2][4];
#pragma unroll
    for (int kk = 0; kk < 4; ++kk)
        af[0][kk] = *reinterpret_cast<const s16x8*>(cbbf + off + (unsigned)kk * 512u);
    off += 2048u;

    int cbase = t0 * 16 + q * 4;   // code index accumulator, +16 per tile

#pragma unroll 2
    for (int t = 0; t < 32; ++t) {
        // unconditional 1-ahead prefetch into the OTHER buffer: at t=31 this
        // reads 4 KiB past cbbf (cnt/thr region -> valid memory, never consumed)
#pragma unroll
        for (int kk = 0; kk < 4; ++kk)
            af[(t + 1) & 1][kk] = *reinterpret_cast<const s16x8*>(
                cbbf + off + (unsigned)kk * 512u);
        off += 2048u;

        const s16x8* cur = af[t & 1];

        f32x4 acc[4];
#pragma unroll
        for (int xt = 0; xt < 4; ++xt) acc[xt] = (f32x4){0.f, 0.f, 0.f, 0.f};
#pragma unroll
        for (int kk = 0; kk < 4; ++kk)
#pragma unroll
            for (int xt = 0; xt < 4; ++xt)
                acc[xt] = __builtin_amdgcn_mfma_f32_16x16x32_bf16(
                    cur[kk], bf[xt][kk], acc[xt], 0, 0, 0);

        // fixed-threshold emission into LDS queue (rare: ~6 per row over scan)
#pragma unroll
        for (int xt = 0; xt < 4; ++xt) {
            const float mx = fmaxf(fmaxf(acc[xt][0], acc[xt][1]),
                                   fmaxf(acc[xt][2], acc[xt][3]));
            if (mx > thrv[xt]) {
                const int lrow = xt * 16 + r;
#pragma unroll
                for (int j = 0; j < 4; ++j)
                    if (acc[xt][j] > thrv[xt]) {
                        // score > 0 here, so float bits are monotone
                        unsigned int key = ((__float_as_uint(acc[xt][j]) >> 13) << 14)
                                         | (unsigned int)(cbase + j);
                        unsigned int p = atomicAdd(&qcnt[lrow], 1u);  // ds_add_rtn
                        if (p < QDEPTH) {
                            qdat[lrow][p] = key;
                        } else {
                            // overflow fallback: direct global emit (rare)
                            int pos = atomicAdd(&cnt[row0 + lrow], 1);
                            if (pos < CAP) cand[(size_t)(row0 + lrow) * CAP + pos] = key;
                        }
                    }
            }
        }
        cbase += 16;
    }

    // epilogue: one global atomic per non-empty row, bulk store
    __syncthreads();
    if (threadIdx.x < 64) {
        const int lrow = threadIdx.x;
        unsigned int k = qcnt[lrow];
        if (k > QDEPTH) k = QDEPTH;
        if (k) {
            const int grow = row0 + lrow;
            int pos = atomicAdd(&cnt[grow], (int)k);
            for (unsigned int i = 0; i < k; ++i) {
                int p2 = pos + (int)i;
                if (p2 < CAP) cand[(size_t)grow * CAP + p2] = qdat[lrow][i];
            }
        }
    }
}

// ---------------- kernel C: key scan + exact fp32 rescore of near-max + softmax ----------------
__device__ inline void topk3_insert(float s, int i, float& s1, int& i1,
                                    float& s2, int& i2, float& s3, int& i3) {
    if (s > s1 || (s == s1 && i < i1)) {
        s3 = s2; i3 = i2; s2 = s1; i2 = i1; s1 = s; i1 = i;
    } else if (s > s2 || (s == s2 && i < i2)) {
        s3 = s2; i3 = i2; s2 = s; i2 = i;
    } else if (s > s3 || (s == s3 && i < i3)) {
        s3 = s; i3 = i;
    }
}

__device__ inline float dec_key(unsigned int k) {
    return __uint_as_float((k >> 14) << 13);
}

__global__ __launch_bounds__(256) void finalize_kernel(
        const float* __restrict__ x, const float* __restrict__ cb,
        const int* __restrict__ cnt, const unsigned int* __restrict__ cand,
        float* __restrict__ out) {
    const int lane = threadIdx.x & 63;
    const int row  = blockIdx.x * 4 + (threadIdx.x >> 6);

    int c = cnt[row];
    if (c > CAP) c = CAP;
    if (c < 0) c = 0;

    const float2 xv = ((const float2*)x)[(size_t)row * 64 + lane];

    // pass 1: max key (coalesced)
    unsigned int kmax = 0;
    for (int i = lane; i < c; i += 64)
        kmax = max(kmax, cand[(size_t)row * CAP + i]);
#pragma unroll
    for (int d = 1; d < 64; d <<= 1)
        kmax = max(kmax, (unsigned int)__shfl_xor((int)kmax, d));
    const float rthr = dec_key(kmax) - RESCORE_WIN;

    // pass 2: exact-rescore candidates near the max (expected ~2)
    const int BIGI = 0x3FFFFFFF;
    float fs1 = -1e30f, fs2 = -1e30f, fs3 = -1e30f;
    int   fi1 = BIGI,   fi2 = BIGI,   fi3 = BIGI;
    for (int basei = 0; basei < c; basei += 64) {
        const int i = basei + lane;
        unsigned int key = (i < c) ? cand[(size_t)row * CAP + i] : 0u;
        const bool flag = (i < c) && (dec_key(key) > rthr);
        unsigned long long mask = __ballot(flag);
        while (mask) {
            const int b = __ffsll((long long)mask) - 1;
            mask &= mask - 1;
            const int idx = __shfl((int)(key & 16383u), b);
            const float2 cv = ((const float2*)cb)[(size_t)idx * 64 + lane];
            float p = xv.x * cv.x + xv.y * cv.y;
#pragma unroll
            for (int d = 1; d < 64; d <<= 1) p += __shfl_xor(p, d);
            topk3_insert(p, idx, fs1, fi1, fs2, fi2, fs3, fi3);
        }
    }

    // exact softmax over {top-3} U {C-3 zeros}
    const float m  = fmaxf(fs1, 0.f);
    const float e1 = (fi1 != BIGI) ? __expf((fs1 - m) / TAU) : 0.f;
    const float e2 = (fi2 != BIGI) ? __expf((fs2 - m) / TAU) : 0.f;
    const float e3 = (fi3 != BIGI) ? __expf((fs3 - m) / TAU) : 0.f;
    const float denom = e1 + e2 + e3 + (float)(NCODES - 3) * __expf(-m / TAU);
    const float w1 = e1 / denom, w2 = e2 / denom, w3 = e3 / denom;

    const float2* cb2 = (const float2*)cb;
    float ox = 0.f, oy = 0.f;
    if (fi1 != BIGI) { float2 v = cb2[(size_t)fi1 * 64 + lane]; ox += w1 * v.x; oy += w1 * v.y; }
    if (fi2 != BIGI) { float2 v = cb2[(size_t)fi2 * 64 + lane]; ox += w2 * v.x; oy += w2 * v.y; }
    if (fi3 != BIGI) { float2 v = cb2[(size_t)fi3 * 64 + lane]; ox += w3 * v.x; oy += w3 * v.y; }
    ((float2*)out)[(size_t)row * 64 + lane] = make_float2(ox, oy);
}

// ---------------- launch ----------------
extern "C" void kernel_launch(void* const* d_in, const int* in_sizes, int n_in,
                              void* d_out, int out_size, void* d_ws, size_t ws_size,
                              hipStream_t stream) {
    const float* x  = (const float*)d_in[0];
    const float* cb = (const float*)d_in[1];
    char* ws = (char*)d_ws;

    unsigned short* xbf  = (unsigned short*)ws;                         // 2 MiB
    unsigned short* cbbf = (unsigned short*)(ws + (2u << 20));          // 4 MiB
    int* cnt  = (int*)(ws + (6u << 20));                                // 32 KiB
    int* thr  = (int*)(ws + (6u << 20) + (128u << 10));                 // 32 KiB
    unsigned int* cand = (unsigned int*)(ws + (8u << 20));              // 8 MiB
    float* out = (float*)d_out;

    hipLaunchKernelGGL(convert_kernel,   dim3(1600), dim3(256), 0, stream, x, cb, xbf, cbbf, cnt, thr);
    hipLaunchKernelGGL(seed_kernel,      dim3(1024), dim3(256), 0, stream, xbf, cbbf, thr);
    hipLaunchKernelGGL(gemm_topk_kernel, dim3(1024), dim3(256), 0, stream, xbf, cbbf, thr, cnt, cand);
    hipLaunchKernelGGL(finalize_kernel,  dim3(2048), dim3(256), 0, stream, x, cb, cnt, cand, out);
}